// Round 14
// baseline (156.087 us; speedup 1.0000x reference)
//
#include <hip/hip_runtime.h>
#include <hip/hip_bf16.h>

typedef __attribute__((ext_vector_type(8))) short short8;
typedef __attribute__((ext_vector_type(4))) short short4v;
typedef __attribute__((ext_vector_type(4))) float f32x4;
typedef __attribute__((ext_vector_type(8))) __bf16 bf16x8;

#define BB 8
#define CC 64
#define NN 65536        // H*W = 256*256
#define SPLIT1 64       // k1 blocks per batch (512 total = 2/CU)
#define COLS1 (NN / SPLIT1)   // 1024 cols per block
#define TILE_C 128            // 64 x 128 x 4B = 32 KB per buffer
#define NT1 (COLS1 / TILE_C)  // 8 tiles
#define SPLIT3 128      // k3 blocks per batch

__device__ inline short f2bf(float f) {
    __hip_bfloat16 h = __float2bfloat16(f);
    return __builtin_bit_cast(short, h);
}

// --- MFMA wrapper: tolerate either short8 or bf16x8 builtin signature ---
template <typename V>
__device__ inline auto mfma_bf16_impl(V a, V b, f32x4 c, int)
    -> decltype(__builtin_amdgcn_mfma_f32_16x16x32_bf16(a, b, c, 0, 0, 0)) {
    return __builtin_amdgcn_mfma_f32_16x16x32_bf16(a, b, c, 0, 0, 0);
}
template <typename V>
__device__ inline f32x4 mfma_bf16_impl(V a, V b, f32x4 c, long) {
    bf16x8 a2 = __builtin_bit_cast(bf16x8, a);
    bf16x8 b2 = __builtin_bit_cast(bf16x8, b);
    return __builtin_amdgcn_mfma_f32_16x16x32_bf16(a2, b2, c, 0, 0, 0);
}
__device__ inline f32x4 mfma16(short8 a, short8 b, f32x4 c) {
    return mfma_bf16_impl(a, b, c, 0);
}

// ---- async global->LDS staging of one 64x128 fp32 tile (R6 proven) ----------
__device__ inline void stage_tile(const float* __restrict__ xb, int colbase,
                                  float* buf, int tid) {
    const int half = tid >> 5;
    const int sl   = tid & 31;
#pragma unroll
    for (int i = 0; i < 8; ++i) {
        const int row   = i * 8 + half;                  // 0..63
        const int gbyte = (sl * 16) ^ ((row & 31) << 4); // pre-swizzled source
        const float* gp = xb + (size_t)row * NN + colbase + (gbyte >> 2);
        float* lp = buf + i * 1024 + tid * 4;            // linear LDS dest
        __builtin_amdgcn_global_load_lds(
            (const __attribute__((address_space(1))) void*)gp,
            (__attribute__((address_space(3))) void*)lp, 16, 0, 0);
    }
}

__device__ inline void lds_read8(const float* buf, int row, int c0, float* v) {
    const char* rb = (const char*)(buf + row * TILE_C);
    const int swz = (row & 31) << 4;
    const f32x4 u0 = *reinterpret_cast<const f32x4*>(rb + ((c0 * 4) ^ swz));
    const f32x4 u1 = *reinterpret_cast<const f32x4*>(rb + (((c0 * 4) + 16) ^ swz));
    v[0] = u0[0]; v[1] = u0[1]; v[2] = u0[2]; v[3] = u0[3];
    v[4] = u1[0]; v[5] = u1[1]; v[6] = u1[2]; v[7] = u1[3];
}

__device__ inline short8 cvt8(const float* v) {
    short8 r;
#pragma unroll
    for (int j = 0; j < 8; ++j) r[j] = f2bf(v[j]);
    return r;
}

// ------- Kernel 1: partial Gram + (last block per batch) reduce+softmax ------
// R6's k1 verbatim, plus the rocPRIM "last block done" pattern: the 64th
// finishing block of each batch absorbs k2a+k2b (fixed sp-ascending reduction
// -> bit-identical to the separate kernels). Removes 2 dispatches + 2 edges.
__global__ __launch_bounds__(256) void k1_gram_fused(const float* __restrict__ x,
                                                     float* __restrict__ partialG,
                                                     float* __restrict__ partialS,
                                                     int* __restrict__ counters,
                                                     unsigned short* __restrict__ att,
                                                     float* __restrict__ offs) {
    __shared__ float shm[2 * CC * TILE_C];   // 64 KB: P1 dbuf, then reducer reuse
    __shared__ int is_last;
    const int blk  = blockIdx.x;
    const int b    = blk / SPLIT1;
    const int s    = blk % SPLIT1;
    const int tid  = threadIdx.x;
    const int w    = tid >> 6, lane = tid & 63, lg = lane >> 4, lr = lane & 15;
    const float* xb = x + (size_t)b * CC * NN;
    const int colbase0 = s * COLS1;
    float* lbuf0 = shm;
    float* lbuf1 = shm + CC * TILE_C;

    f32x4 acc[4];
#pragma unroll
    for (int dt = 0; dt < 4; ++dt) acc[dt] = (f32x4){0.f, 0.f, 0.f, 0.f};
    float asum = 0.f;

    stage_tile(xb, colbase0, lbuf0, tid);
    __syncthreads();

    for (int t = 0; t < NT1; ++t) {
        if (t + 1 < NT1)
            stage_tile(xb, colbase0 + (t + 1) * TILE_C,
                       ((t + 1) & 1) ? lbuf1 : lbuf0, tid);
        const float* buf = (t & 1) ? lbuf1 : lbuf0;
#pragma unroll
        for (int kk = 0; kk < TILE_C / 32; ++kk) {
            const int c0 = kk * 32 + lg * 8;
            float av[8];
            lds_read8(buf, w * 16 + lr, c0, av);
#pragma unroll
            for (int j = 0; j < 8; ++j) asum += av[j];
            const short8 af = cvt8(av);
#pragma unroll
            for (int dt = 0; dt < 4; ++dt) {
                float bv[8];
                lds_read8(buf, dt * 16 + lr, c0, bv);
                const short8 bf = cvt8(bv);
                acc[dt] = mfma16(af, bf, acc[dt]);
            }
        }
        __syncthreads();
    }
    // ---- write partial Gram (C/D map: col=lane&15, row=(lane>>4)*4+reg) ----
#pragma unroll
    for (int dt = 0; dt < 4; ++dt) {
#pragma unroll
        for (int r = 0; r < 4; ++r) {
            const int c = w * 16 + lg * 4 + r;
            const int d = dt * 16 + lr;
            partialG[(size_t)blk * 4096 + c * 64 + d] = acc[dt][r];
        }
    }
    float v = asum;
    v += __shfl_xor(v, 16);
    v += __shfl_xor(v, 32);
    if (lg == 0) partialS[blk * CC + w * 16 + lr] = v;

    // ---- last-block-done: release stores, bump per-batch counter ----
    __threadfence();                 // release: partials visible device-wide
    __syncthreads();                 // all threads fenced before the bump
    if (tid == 0)
        is_last = (atomicAdd(&counters[b], 1) == SPLIT1 - 1);
    __syncthreads();
    if (!is_last) return;
    __threadfence();                 // acquire: see all batches' partials

    // =============== absorbed k2a+k2b for batch b (256 threads) =============
    float* mu   = shm;               // [64]
    float* ener = shm + 64;          // [4096]
    if (tid < CC) {
        float ssum = 0.f;
        for (int sp = 0; sp < SPLIT1; ++sp)
            ssum += partialS[(b * SPLIT1 + sp) * CC + tid];
        mu[tid] = ssum * (1.f / NN);
    }
    f32x4 sg[4];
#pragma unroll
    for (int p = 0; p < 4; ++p) sg[p] = (f32x4){0.f, 0.f, 0.f, 0.f};
    for (int sp = 0; sp < SPLIT1; ++sp) {
        const f32x4* base = reinterpret_cast<const f32x4*>(
            partialG + (((size_t)(b * SPLIT1 + sp)) << 12));
#pragma unroll
        for (int p = 0; p < 4; ++p) sg[p] += base[p * 256 + tid];
    }
    const float inv_n = 1.f / NN;
#pragma unroll
    for (int p = 0; p < 4; ++p) {
        f32x4 e = sg[p];
        e[0] *= inv_n; e[1] *= inv_n; e[2] *= inv_n; e[3] *= inv_n;
        *reinterpret_cast<f32x4*>(&ener[(p * 256 + tid) * 4]) = e;
    }
    __syncthreads();
    for (int i = 0; i < 16; ++i) {
        const int c = w * 16 + i;
        const float e = ener[c * 64 + lane] - mu[c] * mu[lane];
        float m = e;
        for (int off = 32; off > 0; off >>= 1) m = fmaxf(m, __shfl_xor(m, off));
        const float ev = __expf(e - m);
        float sum = ev;
        for (int off = 32; off > 0; off >>= 1) sum += __shfl_xor(sum, off);
        const float a = ev / sum;
        att[(b << 12) + c * 64 + lane] = (unsigned short)f2bf(a);
        float o = a * mu[lane];
        for (int off = 32; off > 0; off >>= 1) o += __shfl_xor(o, off);
        if (lane == 0) offs[b * CC + c] = o;
    }
}

// ---------------- Kernel 3: out = gamma * (A @ x - offset) ------------------
// Non-temporal stores keep x resident in Infinity Cache (134 MB < 256 MB L3).
__global__ __launch_bounds__(256) void k3_apply(const float* __restrict__ x,
                                                const unsigned short* __restrict__ att,
                                                const float* __restrict__ offs,
                                                const float* __restrict__ gamma,
                                                float* __restrict__ out) {
    const int blk  = blockIdx.x;
    const int b    = blk / SPLIT3;
    const int s    = blk % SPLIT3;
    const int tid  = threadIdx.x;
    const int w    = tid >> 6, lane = tid & 63, lg = lane >> 4, lr = lane & 15;
    const float g  = gamma[0];

    short8 afr[4][2];
#pragma unroll
    for (int ct = 0; ct < 4; ++ct)
#pragma unroll
        for (int ks = 0; ks < 2; ++ks)
            afr[ct][ks] = *reinterpret_cast<const short8*>(
                att + (((size_t)b) << 12) + (ct * 16 + lr) * 64 + ks * 32 + lg * 8);

    float offv[4][4];
#pragma unroll
    for (int ct = 0; ct < 4; ++ct)
#pragma unroll
        for (int r = 0; r < 4; ++r)
            offv[ct][r] = offs[b * CC + ct * 16 + lg * 4 + r];

    const int colblock = s * (NN / SPLIT3);
    const int GROUPS = (NN / SPLIT3) / (4 * 64);   // =2
    for (int itg = 0; itg < GROUPS; ++itg) {
        const int n0 = colblock + (w * GROUPS + itg) * 64;
        f32x4 acc[4][4];
#pragma unroll
        for (int ph = 0; ph < 4; ++ph)
#pragma unroll
            for (int ct = 0; ct < 4; ++ct) acc[ph][ct] = (f32x4){0.f, 0.f, 0.f, 0.f};

#pragma unroll
        for (int ks = 0; ks < 2; ++ks) {
            short8 bfr[4];
            const int d0 = ks * 32 + lg * 8;
            const float* xp = x + ((size_t)(b * CC + d0)) * NN + n0 + lr * 4;
#pragma unroll
            for (int j = 0; j < 8; ++j) {
                const float4 v = *reinterpret_cast<const float4*>(xp + (size_t)j * NN);
                bfr[0][j] = f2bf(v.x);
                bfr[1][j] = f2bf(v.y);
                bfr[2][j] = f2bf(v.z);
                bfr[3][j] = f2bf(v.w);
            }
#pragma unroll
            for (int ct = 0; ct < 4; ++ct) {
#pragma unroll
                for (int ph = 0; ph < 4; ++ph)
                    acc[ph][ct] = mfma16(afr[ct][ks], bfr[ph], acc[ph][ct]);
            }
        }
#pragma unroll
        for (int ct = 0; ct < 4; ++ct) {
#pragma unroll
            for (int r = 0; r < 4; ++r) {
                const int c = ct * 16 + lg * 4 + r;
                const float o = offv[ct][r];
                f32x4 vs;
                vs[0] = g * (acc[0][ct][r] - o);
                vs[1] = g * (acc[1][ct][r] - o);
                vs[2] = g * (acc[2][ct][r] - o);
                vs[3] = g * (acc[3][ct][r] - o);
                __builtin_nontemporal_store(
                    vs, reinterpret_cast<f32x4*>(out + ((size_t)(b * CC + c)) * NN + n0 + lr * 4));
            }
        }
    }
}

extern "C" void kernel_launch(void* const* d_in, const int* in_sizes, int n_in,
                              void* d_out, int out_size, void* d_ws, size_t ws_size,
                              hipStream_t stream) {
    const float* x     = (const float*)d_in[0];
    const float* gamma = (const float*)d_in[1];
    float* out = (float*)d_out;

    // Partials at the FRONT of d_out (fully overwritten by k3).
    float* partialG = out;                                   // 8*64*4096 floats (8.4 MB)
    float* partialS = out + (size_t)BB * SPLIT1 * 4096;      // 8*64*64 floats
    int*   counters = (int*)d_ws;                            // 8 ints (zeroed below)
    float* offs     = (float*)((char*)d_ws + 1024);          // 512 floats
    unsigned short* att = (unsigned short*)((char*)d_ws + 4096);  // 8*4096 bf16

    hipMemsetAsync(counters, 0, BB * sizeof(int), stream);   // graph memset node
    k1_gram_fused<<<BB * SPLIT1, 256, 0, stream>>>(x, partialG, partialS,
                                                   counters, att, offs);
    k3_apply<<<BB * SPLIT3, 256, 0, stream>>>(x, att, offs, gamma, out);
}